// Round 8
// baseline (443.421 us; speedup 1.0000x reference)
//
#include <hip/hip_runtime.h>

#define F1260 1260

__device__ __forceinline__ float leakyf(float x) { return x >= 0.f ? x : 0.2f * x; }
__device__ __forceinline__ float eluf(float x) { return x > 0.f ? x : expm1f(x); }
__device__ __forceinline__ float sigmoidf(float x) { return 1.f / (1.f + __expf(-x)); }
// fast tanh: exact saturation (exp->inf => 1, exp->0 => -1), ~1e-6 abs err
__device__ __forceinline__ float tanh_fast(float x) { return 1.f - 2.f / (__expf(2.f * x) + 1.f); }

// ws float layout (runtime NPART = 256 or 128 partial slots):
//   0 .. NPART*84          : per-block channel partials (b*84 + ch = sum,
//                            b*84 + 42 + ch = sumsq), plain stores
//   param block pb = ws + NPART*84:
//       pb+0    scale[42]      pb+64   shift[42]
//       pb+128  adjn[7][49]
//       pb+512  WB[180][24]  (per k=c*30+tt: [0..17]=GAT1 hh*3+{si,sj,we},
//                             [18..20]={a2si,a2sj,W2[tt][0]}, 3 pad)
//       pb+4832 bias[84] (b_ih+b_hh)   pb+4928 Wout[147]   pb+5078 bout[7]

// ---------------- kA: BN stats, float4-coalesced ----------------
// r5-exact body; 256 blocks x 320 threads, 128 rows/block (all CUs).
__global__ __launch_bounds__(320) void kA_stats(const float* __restrict__ x,
                                                float* __restrict__ ws, int rows) {
    __shared__ float fs[1260], fq[1260];
    const int t = threadIdx.x;
    const int n0 = blockIdx.x * rows;
    if (t < 315) {
        const int f0 = t * 4;
        float s0 = 0.f, s1 = 0.f, s2 = 0.f, s3 = 0.f;
        float q0 = 0.f, q1 = 0.f, q2 = 0.f, q3 = 0.f;
#pragma unroll 16
        for (int i = 0; i < rows; ++i) {
            const float4 a = *(const float4*)(x + (size_t)(n0 + i) * F1260 + f0);
            s0 += a.x; q0 += a.x * a.x;
            s1 += a.y; q1 += a.y * a.y;
            s2 += a.z; q2 += a.z * a.z;
            s3 += a.w; q3 += a.w * a.w;
        }
        fs[f0 + 0] = s0; fq[f0 + 0] = q0;
        fs[f0 + 1] = s1; fq[f0 + 1] = q1;
        fs[f0 + 2] = s2; fq[f0 + 2] = q2;
        fs[f0 + 3] = s3; fq[f0 + 3] = q3;
    }
    __syncthreads();
    // channel ch = v*6 + c aggregates flat f = c*210 + tt*7 + v over tt
    if (t < 42) {
        const int v = t / 6, c = t % 6;
        float s = 0.f, q = 0.f;
#pragma unroll
        for (int tt = 0; tt < 30; ++tt) {
            const int f = c * 210 + tt * 7 + v;
            s += fs[f];
            q += fq[f];
        }
        ws[blockIdx.x * 84 + t] = s;
        ws[blockIdx.x * 84 + 42 + t] = q;
    }
}

// ---------------- kB: finalize BN, adjacency norm, weight folds ----------------
__global__ __launch_bounds__(256) void kB_setup(
        const float* __restrict__ bn_gamma, const float* __restrict__ bn_beta,
        const float* __restrict__ W1, const float* __restrict__ a1, const float* __restrict__ B1,
        const float* __restrict__ W2, const float* __restrict__ a2, const float* __restrict__ B2,
        const float* __restrict__ b_ih, const float* __restrict__ b_hh,
        const float* __restrict__ W_out, const float* __restrict__ b_out,
        float* __restrict__ ws, int nrep, int N) {
    const int t = threadIdx.x;
    float* pb = ws + (size_t)nrep * 84;
    const int HH[6] = {0, 3, 6, 10, 13, 16};
    const int EH[6] = {0, 3, 6, 0, 3, 6};

    // per-channel BN scale/shift from nrep block partials
    if (t < 42) {
        float s = 0.f, q = 0.f;
        for (int b = 0; b < nrep; ++b) {
            s += ws[b * 84 + t];
            q += ws[b * 84 + 42 + t];
        }
        const float cnt = 30.f * (float)N;
        const float mean = s / cnt;
        const float var = q / cnt - mean * mean;
        const float sc = bn_gamma[t] * rsqrtf(var + 1e-5f);
        pb[t] = sc;
        pb[64 + t] = bn_beta[t] - mean * sc;
    }
    // normalized adjacency: 6 GAT1 heads + GAT2 head0
    if (t >= 64 && t < 71) {
        const int idx = t - 64;
        const float* Bp = (idx < 6) ? (B1 + HH[idx] * 49) : B2;
        float* op = pb + 128 + idx * 49;
        float adj[49];
        for (int i = 0; i < 49; ++i) adj[i] = Bp[i];
        for (int i = 0; i < 7; ++i) adj[i * 8] += 1.f;
        float mn = adj[0], mx = adj[0];
        for (int i = 1; i < 49; ++i) { mn = fminf(mn, adj[i]); mx = fmaxf(mx, adj[i]); }
        const float inv = 1.f / (mx - mn);
        float rinv[7];
        for (int i = 0; i < 7; ++i) {
            float rs = 0.f;
            for (int j = 0; j < 7; ++j) { adj[i * 7 + j] = (adj[i * 7 + j] - mn) * inv; rs += adj[i * 7 + j]; }
            rinv[i] = rsqrtf(rs);
        }
        for (int i = 0; i < 7; ++i)
            for (int j = 0; j < 7; ++j)
                op[i * 7 + j] = adj[i * 7 + j] * rinv[i] * rinv[j];
    }
    // WB: fold a1 into W1 for the 6 live heads, repacked per-k
    for (int task = t; task < 6 * 180; task += 256) {
        const int hh = task / 180, k = task % 180;
        const int h = HH[hh];
        const float* Wp = W1 + ((size_t)h * 180 + k) * 9;
        float si = 0.f, sj = 0.f;
        for (int e = 0; e < 9; ++e) {
            const float w = Wp[e];
            si += w * a1[h * 18 + e];
            sj += w * a1[h * 18 + 9 + e];
        }
        pb[512 + k * 24 + hh * 3 + 0] = si;
        pb[512 + k * 24 + hh * 3 + 1] = sj;
        pb[512 + k * 24 + hh * 3 + 2] = Wp[EH[hh]];
    }
    // WA2 slots (replicated per c): head 0 of l2, f=0 column kept
    if (t < 30) {
        const float* Wp = W2 + t * 10;
        float si = 0.f, sj = 0.f;
        for (int f = 0; f < 10; ++f) {
            const float w = Wp[f];
            si += w * a2[f];
            sj += w * a2[10 + f];
        }
        for (int c = 0; c < 6; ++c) {
            const int k = c * 30 + t;
            pb[512 + k * 24 + 18] = si;
            pb[512 + k * 24 + 19] = sj;
            pb[512 + k * 24 + 20] = Wp[0];
        }
    }
    if (t < 84) pb[4832 + t] = b_ih[t] + b_hh[t];
    if (t < 147) pb[4928 + t] = W_out[t];
    if (t < 7) pb[5078 + t] = b_out[t];
}

// ---------------- kC: fused dots + attention + LSTM + out ----------------
// Single-wave blocks (64 threads, 8 samples); res-overlay LDS (9772 B, r7).
// NEW phase 1: 2-deep register double buffer in a ROLLED 3-iteration loop
// (2 compute copies only). r2's version died of pin-spill; r3's of 12-copy
// unroll mov/I$ bloat; this form keeps buffers in stable registers and the
// body I$-small while issuing each chunk's 30 gathers ~1320 VALU-cycles
// before first use. Occupancy note: resident 1-wave blocks cap at ~8/CU
// (measured r4 vs r7), so ILP -- not LDS -- is the remaining lever.
#define RS 252
__global__ __launch_bounds__(64) void kC_main(const float* __restrict__ x,
        const float* __restrict__ pb, const float* __restrict__ Wih,
        float* __restrict__ outp, int N) {
    __shared__ __align__(16) float sm[2443];
    float* res  = sm;
    float* scsh = sm + 2016;
    float* adjL = sm + 2100;

    const int t = threadIdx.x;
    const int n0 = blockIdx.x * 8;
    const int v = t >> 3, nl = t & 7;

    const float* xb = x + (size_t)(n0 + nl) * F1260 + v;
    float xva[30], xvb[30];

#define LOADCH(dst, cc)                                               \
    {                                                                 \
        const float* xr_ = xb + (cc) * 210;                           \
        _Pragma("unroll")                                             \
        for (int tt = 0; tt < 30; ++tt) dst[tt] = xr_[tt * 7];        \
    }

#define COMPCH(buf, cc)                                               \
    {                                                                 \
        const float sc = scsh[v * 6 + (cc)];                          \
        const float sh = scsh[42 + v * 6 + (cc)];                     \
        const float* wb_ = pb + 512 + ((cc) * 30) * 24;               \
        float g0 = 0.f, g1 = 0.f, g2 = 0.f;                           \
        _Pragma("unroll")                                             \
        for (int tt = 0; tt < 30; ++tt) {                             \
            const float a = buf[tt] * sc + sh;                        \
            const float* w = wb_ + tt * 24;                           \
            _Pragma("unroll")                                         \
            for (int q = 0; q < 18; ++q) s1[q] += a * w[q];           \
            g0 += a * w[18];                                          \
            g1 += a * w[19];                                          \
            g2 += a * w[20];                                          \
        }                                                             \
        float* rp_ = res + nl * RS + 126 + (v * 6 + (cc)) * 3;        \
        rp_[0] = g0; rp_[1] = g1; rp_[2] = g2;                        \
    }

    // issue chunk-0 loads first so their latency overlaps param staging
    if (v < 7) LOADCH(xva, 0)

    // ---- phase 0: params ----
    for (int i = t; i < 84; i += 64) scsh[i] = pb[i < 42 ? i : 22 + i];
    for (int i = t; i < 343; i += 64) adjL[i] = pb[128 + i];
    __syncthreads();

    // ---- phase 1: dots; thread = (v, nl), 56 active; rolled 2-deep pipeline ----
    float s1[18];
#pragma unroll
    for (int i = 0; i < 18; ++i) s1[i] = 0.f;

    if (v < 7) {
        for (int c = 0; c < 6; c += 2) {
            LOADCH(xvb, c + 1)
            COMPCH(xva, c)
            if (c < 4) LOADCH(xva, c + 2)     // uniform branch, skipped last iter
            COMPCH(xvb, c + 1)
        }
#pragma unroll
        for (int q = 0; q < 18; ++q)
            res[nl * RS + v * 18 + q] = s1[q];
    }
    __syncthreads();

    // ---- phase 2: GAT1 heads; thread = (hh, nl) ----
    // Loads by ALL 64 threads (hh=6,7 read in-bounds garbage), then a barrier
    // so the overlay writes below can never pass another lane's s1 reads.
    const int hh = t >> 3, nl2 = t & 7;
    float si[7], sj[7], we[7];
#pragma unroll
    for (int vv = 0; vv < 7; ++vv) {
        const float* rp = res + nl2 * RS + vv * 18 + hh * 3;
        si[vv] = rp[0]; sj[vv] = rp[1]; we[vv] = rp[2];
    }
    __syncthreads();
    if (t < 48) {
        float mxsj = sj[0];
#pragma unroll
        for (int j = 1; j < 7; ++j) mxsj = fmaxf(mxsj, sj[j]);
        float p[7];
#pragma unroll
        for (int i = 0; i < 7; ++i) {
            const float m = leakyf(si[i] + mxsj);   // leaky monotonic -> row max
            float den = 0.f, num = 0.f;
#pragma unroll
            for (int j = 0; j < 7; ++j) {
                const float w = __expf(leakyf(si[i] + sj[j]) - m);
                den += w;
                num += w * we[j];
            }
            p[i] = num / den;
        }
        const float* An = adjL + hh * 49;
#pragma unroll
        for (int i = 0; i < 7; ++i) {
            float r = 0.f;
#pragma unroll
            for (int k = 0; k < 7; ++k) r += An[i * 7 + k] * p[k];
            res[nl2 * RS + hh * 7 + i] = eluf(r);        // xs0 overlay [0..42)
        }
    }
    // ---- phase 2b: GAT2 softmax-over-channels; thread = (i, nl), 56 active ----
    // reads g [126..252), writes h2t overlay [84..126) -- disjoint, no hazard
    if (t < 56) {
        const int i = t >> 3;
        float si2[6];
#pragma unroll
        for (int c = 0; c < 6; ++c)
            si2[c] = res[nl2 * RS + 126 + (i * 6 + c) * 3];
        float hc[6];
#pragma unroll
        for (int c = 0; c < 6; ++c) hc[c] = 0.f;
#pragma unroll
        for (int j = 0; j < 7; ++j) {
            float s[6];
            float m = -1e30f;
#pragma unroll
            for (int c = 0; c < 6; ++c) {
                const float* rp = res + nl2 * RS + 126 + (j * 6 + c) * 3;
                s[c] = leakyf(si2[c] + rp[1]);
                m = fmaxf(m, s[c]);
            }
            float den = 0.f;
#pragma unroll
            for (int c = 0; c < 6; ++c) { s[c] = __expf(s[c] - m); den += s[c]; }
            const float rd = 1.f / den;
#pragma unroll
            for (int c = 0; c < 6; ++c) {
                const float wh0 = res[nl2 * RS + 126 + (j * 6 + c) * 3 + 2];
                hc[c] += wh0 * s[c] * rd;
            }
        }
#pragma unroll
        for (int c = 0; c < 6; ++c)
            res[nl2 * RS + 84 + i * 6 + c] = hc[c];      // h2t overlay [84..126)
    }
    __syncthreads();

    // ---- phase 3: GAT2 adj multiply; thread = (c, nl), 48 active ----
    // reads h2t [84..126), writes xs0 [42..84) -- disjoint
    if (t < 48) {
        const int c = t >> 3;
        const float* An2 = adjL + 6 * 49;
        float h[7];
#pragma unroll
        for (int u = 0; u < 7; ++u) h[u] = res[nl2 * RS + 84 + u * 6 + c];
#pragma unroll
        for (int vv = 0; vv < 7; ++vv) {
            float r = 0.f;
#pragma unroll
            for (int u = 0; u < 7; ++u) r += h[u] * An2[u * 7 + vv];
            res[nl2 * RS + 42 + c * 7 + vv] = eluf(r);   // xs0 overlay [42..84)
        }
    }
    __syncthreads();

    // ---- phase 4: LSTM step 0; thread = (g8, nl), all 64; float4 reads ----
    // reads xs0 [0..84) (row base 1008B-aligned), writes h1s overlay [126..148)
    {
        const int g8 = t >> 3;
        const float* bias = pb + 4832;
        const float4* xs4 = (const float4*)(res + nl2 * RS);
        for (int gi = g8; gi < 21; gi += 8) {
            float ga = bias[gi], gg = bias[42 + gi], go = bias[63 + gi];
            const float4* wa = (const float4*)(Wih + gi * 84);
            const float4* wg = (const float4*)(Wih + (42 + gi) * 84);
            const float4* wo = (const float4*)(Wih + (63 + gi) * 84);
#pragma unroll
            for (int k = 0; k < 21; ++k) {
                const float4 xv = xs4[k];
                const float4 a4 = wa[k];
                const float4 g4 = wg[k];
                const float4 o4 = wo[k];
                ga += xv.x * a4.x + xv.y * a4.y + xv.z * a4.z + xv.w * a4.w;
                gg += xv.x * g4.x + xv.y * g4.y + xv.z * g4.z + xv.w * g4.w;
                go += xv.x * o4.x + xv.y * o4.y + xv.z * o4.z + xv.w * o4.w;
            }
            const float c1 = sigmoidf(ga) * tanh_fast(gg);
            res[nl2 * RS + 126 + gi] = sigmoidf(go) * tanh_fast(c1);
        }
    }
    __syncthreads();

    // ---- phase 5: output projection; thread = nl*7+j, 56 active, coalesced ----
    if (t < 56) {
        const int n5 = t / 7, j = t - n5 * 7;
        const float* Wout = pb + 4928;
        float r = pb[5078 + j];
#pragma unroll
        for (int m = 0; m < 21; ++m) r += res[n5 * RS + 126 + m] * Wout[j * 21 + m];
        outp[(size_t)n0 * 7 + t] = r;
    }
}

extern "C" void kernel_launch(void* const* d_in, const int* in_sizes, int n_in,
                              void* d_out, int out_size, void* d_ws, size_t ws_size,
                              hipStream_t stream) {
    const int N = in_sizes[0] / F1260;

    const float* x        = (const float*)d_in[0];
    const float* bn_gamma = (const float*)d_in[1];
    const float* bn_beta  = (const float*)d_in[2];
    const float* W1       = (const float*)d_in[3];
    const float* a1       = (const float*)d_in[4];
    const float* B1       = (const float*)d_in[5];
    const float* W2       = (const float*)d_in[6];
    const float* a2       = (const float*)d_in[7];
    const float* B2       = (const float*)d_in[8];
    const float* W_ih     = (const float*)d_in[9];
    // d_in[10] = W_hh unused (h0 = 0 -> only LSTM step 0 matters)
    const float* b_ih     = (const float*)d_in[11];
    const float* b_hh     = (const float*)d_in[12];
    const float* W_out    = (const float*)d_in[13];
    const float* b_out    = (const float*)d_in[14];

    float* wsf = (float*)d_ws;

    // 256 partial slots (full-CU kA grid) if workspace allows, else 128
    const int npart = (ws_size >= (size_t)(256 * 84 + 5085 + 64) * sizeof(float)) ? 256 : 128;

    // no memset needed: kA writes its partials with plain stores

    kA_stats<<<dim3(npart), dim3(320), 0, stream>>>(x, wsf, N / npart);
    kB_setup<<<dim3(1), dim3(256), 0, stream>>>(bn_gamma, bn_beta, W1, a1, B1,
                                                W2, a2, B2, b_ih, b_hh,
                                                W_out, b_out, wsf, npart, N);
    kC_main<<<dim3(N / 8), dim3(64), 0, stream>>>(x, wsf + (size_t)npart * 84,
                                                  W_ih, (float*)d_out, N);
}

// Round 9
// 337.168 us; speedup vs baseline: 1.3151x; 1.3151x over previous
//
#include <hip/hip_runtime.h>

#define F1260 1260
#define NPART 128        // kA blocks; partials = NPART*84 floats
#define PB_OFF (NPART * 84)

__device__ __forceinline__ float leakyf(float x) { return x >= 0.f ? x : 0.2f * x; }
__device__ __forceinline__ float eluf(float x) { return x > 0.f ? x : expm1f(x); }
__device__ __forceinline__ float sigmoidf(float x) { return 1.f / (1.f + __expf(-x)); }
// fast tanh: exact saturation (exp->inf => 1, exp->0 => -1), ~1e-6 abs err
__device__ __forceinline__ float tanh_fast(float x) { return 1.f - 2.f / (__expf(2.f * x) + 1.f); }

// ws float layout:
//   0 .. NPART*84 : per-block channel partials (b*84+ch = sum, b*84+42+ch = sq)
//   param block pb = ws + PB_OFF:
//       pb+0    scale[42]      pb+64   shift[42]
//       pb+128  adjn[7][49]
//       pb+512  WB[180][24]  (per k=c*30+tt: [0..17]=GAT1 hh*3+{si,sj,we},
//                             [18..20]={a2si,a2sj,W2[tt][0]}, 3 pad)
//       pb+4832 bias[84] (b_ih+b_hh)   pb+4928 Wout[147]   pb+5078 bout[7]
//   total ~62 KB

// ---------------- kA: BN stats, float4-coalesced ----------------
// r5-exact (best measured "rest"): 128 blocks x 320 threads, 256 rows/block.
// (256-block and 640-thread variants both measured worse: r6/r7/r8.)
__global__ __launch_bounds__(320) void kA_stats(const float* __restrict__ x,
                                                float* __restrict__ ws, int rows) {
    __shared__ float fs[1260], fq[1260];
    const int t = threadIdx.x;
    const int n0 = blockIdx.x * rows;
    if (t < 315) {
        const int f0 = t * 4;
        float s0 = 0.f, s1 = 0.f, s2 = 0.f, s3 = 0.f;
        float q0 = 0.f, q1 = 0.f, q2 = 0.f, q3 = 0.f;
#pragma unroll 16
        for (int i = 0; i < rows; ++i) {
            const float4 a = *(const float4*)(x + (size_t)(n0 + i) * F1260 + f0);
            s0 += a.x; q0 += a.x * a.x;
            s1 += a.y; q1 += a.y * a.y;
            s2 += a.z; q2 += a.z * a.z;
            s3 += a.w; q3 += a.w * a.w;
        }
        fs[f0 + 0] = s0; fq[f0 + 0] = q0;
        fs[f0 + 1] = s1; fq[f0 + 1] = q1;
        fs[f0 + 2] = s2; fq[f0 + 2] = q2;
        fs[f0 + 3] = s3; fq[f0 + 3] = q3;
    }
    __syncthreads();
    // channel ch = v*6 + c aggregates flat f = c*210 + tt*7 + v over tt
    if (t < 42) {
        const int v = t / 6, c = t % 6;
        float s = 0.f, q = 0.f;
#pragma unroll
        for (int tt = 0; tt < 30; ++tt) {
            const int f = c * 210 + tt * 7 + v;
            s += fs[f];
            q += fq[f];
        }
        ws[blockIdx.x * 84 + t] = s;
        ws[blockIdx.x * 84 + 42 + t] = q;
    }
}

// ---------------- kB: finalize BN, adjacency norm, weight folds ----------------
__global__ __launch_bounds__(256) void kB_setup(
        const float* __restrict__ bn_gamma, const float* __restrict__ bn_beta,
        const float* __restrict__ W1, const float* __restrict__ a1, const float* __restrict__ B1,
        const float* __restrict__ W2, const float* __restrict__ a2, const float* __restrict__ B2,
        const float* __restrict__ b_ih, const float* __restrict__ b_hh,
        const float* __restrict__ W_out, const float* __restrict__ b_out,
        float* __restrict__ ws, int N) {
    const int t = threadIdx.x;
    float* pb = ws + PB_OFF;
    const int HH[6] = {0, 3, 6, 10, 13, 16};
    const int EH[6] = {0, 3, 6, 0, 3, 6};

    // per-channel BN scale/shift from NPART block partials
    if (t < 42) {
        float s = 0.f, q = 0.f;
        for (int b = 0; b < NPART; ++b) {
            s += ws[b * 84 + t];
            q += ws[b * 84 + 42 + t];
        }
        const float cnt = 30.f * (float)N;
        const float mean = s / cnt;
        const float var = q / cnt - mean * mean;
        const float sc = bn_gamma[t] * rsqrtf(var + 1e-5f);
        pb[t] = sc;
        pb[64 + t] = bn_beta[t] - mean * sc;
    }
    // normalized adjacency: 6 GAT1 heads + GAT2 head0
    if (t >= 64 && t < 71) {
        const int idx = t - 64;
        const float* Bp = (idx < 6) ? (B1 + HH[idx] * 49) : B2;
        float* op = pb + 128 + idx * 49;
        float adj[49];
        for (int i = 0; i < 49; ++i) adj[i] = Bp[i];
        for (int i = 0; i < 7; ++i) adj[i * 8] += 1.f;
        float mn = adj[0], mx = adj[0];
        for (int i = 1; i < 49; ++i) { mn = fminf(mn, adj[i]); mx = fmaxf(mx, adj[i]); }
        const float inv = 1.f / (mx - mn);
        float rinv[7];
        for (int i = 0; i < 7; ++i) {
            float rs = 0.f;
            for (int j = 0; j < 7; ++j) { adj[i * 7 + j] = (adj[i * 7 + j] - mn) * inv; rs += adj[i * 7 + j]; }
            rinv[i] = rsqrtf(rs);
        }
        for (int i = 0; i < 7; ++i)
            for (int j = 0; j < 7; ++j)
                op[i * 7 + j] = adj[i * 7 + j] * rinv[i] * rinv[j];
    }
    // WB: fold a1 into W1 for the 6 live heads, repacked per-k
    for (int task = t; task < 6 * 180; task += 256) {
        const int hh = task / 180, k = task % 180;
        const int h = HH[hh];
        const float* Wp = W1 + ((size_t)h * 180 + k) * 9;
        float si = 0.f, sj = 0.f;
        for (int e = 0; e < 9; ++e) {
            const float w = Wp[e];
            si += w * a1[h * 18 + e];
            sj += w * a1[h * 18 + 9 + e];
        }
        pb[512 + k * 24 + hh * 3 + 0] = si;
        pb[512 + k * 24 + hh * 3 + 1] = sj;
        pb[512 + k * 24 + hh * 3 + 2] = Wp[EH[hh]];
    }
    // WA2 slots (replicated per c): head 0 of l2, f=0 column kept
    if (t < 30) {
        const float* Wp = W2 + t * 10;
        float si = 0.f, sj = 0.f;
        for (int f = 0; f < 10; ++f) {
            const float w = Wp[f];
            si += w * a2[f];
            sj += w * a2[10 + f];
        }
        for (int c = 0; c < 6; ++c) {
            const int k = c * 30 + t;
            pb[512 + k * 24 + 18] = si;
            pb[512 + k * 24 + 19] = sj;
            pb[512 + k * 24 + 20] = Wp[0];
        }
    }
    if (t < 84) pb[4832 + t] = b_ih[t] + b_hh[t];
    if (t < 147) pb[4928 + t] = W_out[t];
    if (t < 7) pb[5078 + t] = b_out[t];
}

// ---------------- kC: fused dots + attention + LSTM + out ----------------
// NEW: 2-wave blocks (128 threads, 16 samples) to beat the ~8 resident
// WORKGROUPS/CU cap observed in r4/r7 (occupancy ~8 waves/CU independent of
// LDS headroom). Wave w owns samples w*8..w*8+7; every phase mask is
// wave-local (v/hh/i/c = (t>>3)&7, nl = (t>>6)*8 + (t&7)), so waves only
// interact at barriers. Phase-1 is the r7-exact simple chunk loop (hand
// pipelining regressed in r2/r3/r8 -- closed).
// res-overlay layout per row (252 floats, r7-verified):
//   [0..126) s1 -> xs0[0..84) + h2t[84..126);  [126..252) g -> h1s[126..148)
// LDS: res 16x252 + scsh 84 + adjL 343 = 4459 floats = 17836 B.
#define RS 252
__global__ __launch_bounds__(128) void kC_main(const float* __restrict__ x,
        const float* __restrict__ pb, const float* __restrict__ Wih,
        float* __restrict__ outp, int N) {
    __shared__ __align__(16) float sm[4459];
    float* res  = sm;
    float* scsh = sm + 4032;
    float* adjL = sm + 4116;

    const int t = threadIdx.x;
    const int n0 = blockIdx.x * 16;
    const int v = (t >> 3) & 7;              // wave-local role 0..7
    const int nl = ((t >> 6) << 3) + (t & 7);  // sample row 0..15

    // ---- phase 0: params ----
    for (int i = t; i < 84; i += 128) scsh[i] = pb[i < 42 ? i : 22 + i];
    for (int i = t; i < 343; i += 128) adjL[i] = pb[128 + i];
    __syncthreads();

    // ---- phase 1: dots; thread = (v, nl), 112 active ----
    if (v < 7) {
        float s1[18];
#pragma unroll
        for (int i = 0; i < 18; ++i) s1[i] = 0.f;
        const float* xb = x + (size_t)(n0 + nl) * F1260 + v;
        const float* WB = pb + 512;
        for (int c = 0; c < 6; ++c) {
            const float sc = scsh[v * 6 + c];
            const float sh = scsh[42 + v * 6 + c];
            const float* xr = xb + c * 210;
            const float* wb = WB + (c * 30) * 24;
            float xv[30];
#pragma unroll
            for (int tt = 0; tt < 30; ++tt) xv[tt] = xr[tt * 7];   // batch loads
            float g0 = 0.f, g1 = 0.f, g2 = 0.f;
#pragma unroll
            for (int tt = 0; tt < 30; ++tt) {
                const float a = xv[tt] * sc + sh;
                const float* w = wb + tt * 24;                      // wave-uniform -> s_loads
#pragma unroll
                for (int q = 0; q < 18; ++q) s1[q] += a * w[q];
                g0 += a * w[18];
                g1 += a * w[19];
                g2 += a * w[20];
            }
            float* rp = res + nl * RS + 126 + (v * 6 + c) * 3;
            rp[0] = g0; rp[1] = g1; rp[2] = g2;
        }
#pragma unroll
        for (int q = 0; q < 18; ++q)
            res[nl * RS + v * 18 + q] = s1[q];
    }
    __syncthreads();

    // ---- phase 2: GAT1 heads; role hh = v ----
    // Pre-load by ALL threads (hh=6,7 read in-bounds garbage), then a barrier:
    // REQUIRED for cross-wave safety -- no overlay write may precede another
    // wave's s1 reads.
    const int hh = v;
    float si[7], sj[7], we[7];
#pragma unroll
    for (int vv = 0; vv < 7; ++vv) {
        const float* rp = res + nl * RS + vv * 18 + hh * 3;
        si[vv] = rp[0]; sj[vv] = rp[1]; we[vv] = rp[2];
    }
    __syncthreads();
    if (hh < 6) {
        float mxsj = sj[0];
#pragma unroll
        for (int j = 1; j < 7; ++j) mxsj = fmaxf(mxsj, sj[j]);
        float p[7];
#pragma unroll
        for (int i = 0; i < 7; ++i) {
            const float m = leakyf(si[i] + mxsj);   // leaky monotonic -> row max
            float den = 0.f, num = 0.f;
#pragma unroll
            for (int j = 0; j < 7; ++j) {
                const float w = __expf(leakyf(si[i] + sj[j]) - m);
                den += w;
                num += w * we[j];
            }
            p[i] = num / den;
        }
        const float* An = adjL + hh * 49;
#pragma unroll
        for (int i = 0; i < 7; ++i) {
            float r = 0.f;
#pragma unroll
            for (int k = 0; k < 7; ++k) r += An[i * 7 + k] * p[k];
            res[nl * RS + hh * 7 + i] = eluf(r);        // xs0 overlay [0..42)
        }
    }
    // ---- phase 2b: GAT2 softmax-over-channels; role i = v (<7) ----
    // reads g [126..252) of own row, writes h2t overlay [84..126) -- disjoint
    if (v < 7) {
        const int i = v;
        float si2[6];
#pragma unroll
        for (int c = 0; c < 6; ++c)
            si2[c] = res[nl * RS + 126 + (i * 6 + c) * 3];
        float hc[6];
#pragma unroll
        for (int c = 0; c < 6; ++c) hc[c] = 0.f;
#pragma unroll
        for (int j = 0; j < 7; ++j) {
            float s[6];
            float m = -1e30f;
#pragma unroll
            for (int c = 0; c < 6; ++c) {
                const float* rp = res + nl * RS + 126 + (j * 6 + c) * 3;
                s[c] = leakyf(si2[c] + rp[1]);
                m = fmaxf(m, s[c]);
            }
            float den = 0.f;
#pragma unroll
            for (int c = 0; c < 6; ++c) { s[c] = __expf(s[c] - m); den += s[c]; }
            const float rd = 1.f / den;
#pragma unroll
            for (int c = 0; c < 6; ++c) {
                const float wh0 = res[nl * RS + 126 + (j * 6 + c) * 3 + 2];
                hc[c] += wh0 * s[c] * rd;
            }
        }
#pragma unroll
        for (int c = 0; c < 6; ++c)
            res[nl * RS + 84 + i * 6 + c] = hc[c];      // h2t overlay [84..126)
    }
    __syncthreads();

    // ---- phase 3: GAT2 adj multiply; role c = v (<6) ----
    // reads h2t [84..126) of own row, writes xs0 [42..84) -- disjoint
    if (v < 6) {
        const int c = v;
        const float* An2 = adjL + 6 * 49;
        float h[7];
#pragma unroll
        for (int u = 0; u < 7; ++u) h[u] = res[nl * RS + 84 + u * 6 + c];
#pragma unroll
        for (int vv = 0; vv < 7; ++vv) {
            float r = 0.f;
#pragma unroll
            for (int u = 0; u < 7; ++u) r += h[u] * An2[u * 7 + vv];
            res[nl * RS + 42 + c * 7 + vv] = eluf(r);   // xs0 overlay [42..84)
        }
    }
    __syncthreads();

    // ---- phase 4: LSTM step 0; role g8 = v, all threads; float4 reads ----
    // reads xs0 [0..84) (row base 1008B-aligned), writes h1s overlay [126..148)
    {
        const int g8 = v + ((t >> 3) & 8 ? 0 : 0);   // v in 0..7
        const float* bias = pb + 4832;
        const float4* xs4 = (const float4*)(res + nl * RS);
        for (int gi = g8; gi < 21; gi += 8) {
            float ga = bias[gi], gg = bias[42 + gi], go = bias[63 + gi];
            const float4* wa = (const float4*)(Wih + gi * 84);
            const float4* wg = (const float4*)(Wih + (42 + gi) * 84);
            const float4* wo = (const float4*)(Wih + (63 + gi) * 84);
#pragma unroll
            for (int k = 0; k < 21; ++k) {
                const float4 xv = xs4[k];
                const float4 a4 = wa[k];
                const float4 g4 = wg[k];
                const float4 o4 = wo[k];
                ga += xv.x * a4.x + xv.y * a4.y + xv.z * a4.z + xv.w * a4.w;
                gg += xv.x * g4.x + xv.y * g4.y + xv.z * g4.z + xv.w * g4.w;
                go += xv.x * o4.x + xv.y * o4.y + xv.z * o4.z + xv.w * o4.w;
            }
            const float c1 = sigmoidf(ga) * tanh_fast(gg);
            res[nl * RS + 126 + gi] = sigmoidf(go) * tanh_fast(c1);
        }
    }
    __syncthreads();

    // ---- phase 5: output projection; thread = n5*7+j, 112 active, coalesced ----
    if (t < 112) {
        const int n5 = t / 7, j = t - n5 * 7;
        const float* Wout = pb + 4928;
        float r = pb[5078 + j];
#pragma unroll
        for (int m = 0; m < 21; ++m) r += res[n5 * RS + 126 + m] * Wout[j * 21 + m];
        outp[(size_t)n0 * 7 + t] = r;
    }
}

extern "C" void kernel_launch(void* const* d_in, const int* in_sizes, int n_in,
                              void* d_out, int out_size, void* d_ws, size_t ws_size,
                              hipStream_t stream) {
    const int N = in_sizes[0] / F1260;

    const float* x        = (const float*)d_in[0];
    const float* bn_gamma = (const float*)d_in[1];
    const float* bn_beta  = (const float*)d_in[2];
    const float* W1       = (const float*)d_in[3];
    const float* a1       = (const float*)d_in[4];
    const float* B1       = (const float*)d_in[5];
    const float* W2       = (const float*)d_in[6];
    const float* a2       = (const float*)d_in[7];
    const float* B2       = (const float*)d_in[8];
    const float* W_ih     = (const float*)d_in[9];
    // d_in[10] = W_hh unused (h0 = 0 -> only LSTM step 0 matters)
    const float* b_ih     = (const float*)d_in[11];
    const float* b_hh     = (const float*)d_in[12];
    const float* W_out    = (const float*)d_in[13];
    const float* b_out    = (const float*)d_in[14];

    float* wsf = (float*)d_ws;

    // no memset needed: kA writes its partials with plain stores

    kA_stats<<<dim3(NPART), dim3(320), 0, stream>>>(x, wsf, N / NPART);
    kB_setup<<<dim3(1), dim3(256), 0, stream>>>(bn_gamma, bn_beta, W1, a1, B1,
                                                W2, a2, B2, b_ih, b_hh,
                                                W_out, b_out, wsf, N);
    kC_main<<<dim3(N / 16), dim3(128), 0, stream>>>(x, wsf + PB_OFF, W_ih, (float*)d_out, N);
}